// Round 7
// baseline (305.187 us; speedup 1.0000x reference)
//
#include <hip/hip_runtime.h>
#include <hip/hip_bf16.h>
#include <stdint.h>

typedef unsigned short ushortx;
typedef __attribute__((ext_vector_type(8))) short bs8;   // 8 bf16 (4 VGPRs)
typedef __attribute__((ext_vector_type(4))) float f32x4; // MFMA acc

// ---------------------------------------------------------------------------
// Compile-time octahedral tables (replicates the reference's itertools order)
// ---------------------------------------------------------------------------
struct Tab {
    int shift[24][24];
    int rot[24][27];
};

constexpr Tab make_tab() {
    Tab t{};
    int mats[24][3][3] = {};
    {
        const int perms[6][3] = {{0,1,2},{0,2,1},{1,0,2},{1,2,0},{2,0,1},{2,1,0}};
        const int sgns[8][3]  = {{1,1,1},{1,1,-1},{1,-1,1},{1,-1,-1},
                                 {-1,1,1},{-1,1,-1},{-1,-1,1},{-1,-1,-1}};
        int n = 0;
        for (int pi = 0; pi < 6; ++pi)
            for (int si = 0; si < 8; ++si) {
                int M[3][3] = {};
                for (int i = 0; i < 3; ++i) M[i][perms[pi][i]] = sgns[si][i];
                int det = M[0][0]*(M[1][1]*M[2][2]-M[1][2]*M[2][1])
                        - M[0][1]*(M[1][0]*M[2][2]-M[1][2]*M[2][0])
                        + M[0][2]*(M[1][0]*M[2][1]-M[1][1]*M[2][0]);
                if (det == 1) {
                    for (int i = 0; i < 3; ++i)
                        for (int j = 0; j < 3; ++j) mats[n][i][j] = M[i][j];
                    ++n;
                }
            }
    }
    for (int g = 0; g < 24; ++g)
        for (int h = 0; h < 24; ++h) {
            int P[3][3] = {};
            for (int i = 0; i < 3; ++i)
                for (int j = 0; j < 3; ++j) {
                    int s = 0;
                    for (int e = 0; e < 3; ++e) s += mats[g][e][i] * mats[h][e][j];
                    P[i][j] = s;
                }
            for (int k = 0; k < 24; ++k) {
                bool eq = true;
                for (int i = 0; i < 3; ++i)
                    for (int j = 0; j < 3; ++j)
                        if (mats[k][i][j] != P[i][j]) eq = false;
                if (eq) t.shift[g][h] = k;
            }
        }
    for (int g = 0; g < 24; ++g)
        for (int j = 0; j < 27; ++j) {
            int co[3] = { j/9 - 1, (j/3)%3 - 1, j%3 - 1 };
            int src[3] = {};
            for (int d = 0; d < 3; ++d) {
                int s = 0;
                for (int e = 0; e < 3; ++e) s += co[e] * mats[g][e][d];
                src[d] = s + 1;
            }
            t.rot[g][j] = src[0]*9 + src[1]*3 + src[2];
        }
    return t;
}

__constant__ Tab TAB = make_tab();

#define GG 24
#define OO 16
#define II 16
#define PVOL 32768
#define MCH 384
#define KCH 384
#define KG  48      // 384 k / 8 per 16B chunk

// bf16 helpers (RNE)
__device__ __forceinline__ unsigned f2bfu(float f) {
    union { float f; unsigned u; } a; a.f = f;
    unsigned r = a.u + 0x7FFFu + ((a.u >> 16) & 1u);
    return r >> 16;
}
__device__ __forceinline__ float bfu2f(unsigned h) {
    union { unsigned u; float f; } a; a.u = h << 16;
    return a.f;
}

#define GLOAD16(gp, lp) \
    __builtin_amdgcn_global_load_lds((const __attribute__((address_space(1))) void*)(gp), \
                                     (__attribute__((address_space(3))) void*)(lp), 16, 0, 0)

// ---------------------------------------------------------------------------
// build_weights2: W2 bf16 [384 m][768 k2] where each 32-k block of the
// original k is stored as [32 hi | 32 lo]  (row = 1536 B), + wt fp32 [384][27]
// ---------------------------------------------------------------------------
__global__ void build_weights2(const float* __restrict__ gw, const float* __restrict__ tw,
                               ushortx* __restrict__ w2, float* __restrict__ wt) {
    int idx = blockIdx.x * 256 + threadIdx.x;
    if (idx < MCH * KCH) {
        int m = idx / KCH, k = idx % KCH;
        int o = m / GG, z = m % GG;
        int i = k / GG, g = k % GG;
        float w = gw[TAB.shift[z][g] * (OO * II) + o * II + i];
        unsigned h = f2bfu(w);
        unsigned l = f2bfu(w - bfu2f(h));
        size_t base = (size_t)m * 768 + (k >> 5) * 64 + (k & 31);
        w2[base]      = (ushortx)h;
        w2[base + 32] = (ushortx)l;
    } else {
        int r = idx - MCH * KCH;
        if (r < MCH * 27) {
            int c = r / 27, j = r % 27;
            wt[r] = tw[(c / GG) * 27 + TAB.rot[c % GG][j]];
        }
    }
}

// ---------------------------------------------------------------------------
// convert_x v3 (unchanged, proven): fp32 X -> Xhi/Xlo bf16 chunk planes,
// pure-register packing (no scratch).
// ---------------------------------------------------------------------------
__global__ __launch_bounds__(256) void convert_x(const float* __restrict__ X,
                                                 uint4* __restrict__ Xhi,
                                                 uint4* __restrict__ Xlo) {
    const int n0 = blockIdx.x * 256, kg = blockIdx.y, b = blockIdx.z;
    __shared__ float s[8][260];
    const int t = threadIdx.x;
    const float* Xb = X + ((size_t)b * KCH + kg * 8) * PVOL;

    {
        const int r0 = t >> 6, c4 = (t & 63) * 4;
        float4 v0 = *(const float4*)&Xb[(size_t)r0 * PVOL + n0 + c4];
        float4 v1 = *(const float4*)&Xb[(size_t)(r0 + 4) * PVOL + n0 + c4];
        *(float4*)&s[r0][c4] = v0;
        *(float4*)&s[r0 + 4][c4] = v1;
    }
    __syncthreads();

    const int n = t;
    float f0 = s[0][n], f1 = s[1][n], f2 = s[2][n], f3 = s[3][n];
    float f4 = s[4][n], f5 = s[5][n], f6 = s[6][n], f7 = s[7][n];

    unsigned h0 = f2bfu(f0), h1 = f2bfu(f1), h2 = f2bfu(f2), h3 = f2bfu(f3);
    unsigned h4 = f2bfu(f4), h5 = f2bfu(f5), h6 = f2bfu(f6), h7 = f2bfu(f7);
    uint4 H = { h0 | (h1 << 16), h2 | (h3 << 16), h4 | (h5 << 16), h6 | (h7 << 16) };

    unsigned l0 = f2bfu(f0 - bfu2f(h0)), l1 = f2bfu(f1 - bfu2f(h1));
    unsigned l2 = f2bfu(f2 - bfu2f(h2)), l3 = f2bfu(f3 - bfu2f(h3));
    unsigned l4 = f2bfu(f4 - bfu2f(h4)), l5 = f2bfu(f5 - bfu2f(h5));
    unsigned l6 = f2bfu(f6 - bfu2f(h6)), l7 = f2bfu(f7 - bfu2f(h7));
    uint4 L = { l0 | (l1 << 16), l2 | (l3 << 16), l4 | (l5 << 16), l6 | (l7 << 16) };

    const size_t ci = ((size_t)(b * KG + kg)) * PVOL + n0 + n;   // 16B-chunk index
    Xhi[ci] = H;
    Xlo[ci] = L;
}

// ---------------------------------------------------------------------------
// gemm_mfma v4: v3 + 2-phase double-buffered pipeline with counted vmcnt.
//   STAGE(it+1) issued BEFORE compute(it); s_waitcnt vmcnt(8) waits only the
//   current tile's 8 loads (prefetch stays in flight); raw s_barrier (no
//   __syncthreads -> no vmcnt(0) drain). T3-min + T4 per catalog.
// ---------------------------------------------------------------------------
__global__ __launch_bounds__(256) void gemm_mfma(const ushortx* __restrict__ W2,
                                                 const uint4* __restrict__ Xhi,
                                                 const uint4* __restrict__ Xlo,
                                                 const float* __restrict__ gbias,
                                                 float* __restrict__ Y) {
    __shared__ ushortx As[2][8192];   // [buf][128 m][ hi 64B | lo 64B ] swizzled
    __shared__ ushortx Bs[2][8192];
    const int b = blockIdx.z, m0 = blockIdx.y * 128, n0 = blockIdx.x * 128;
    const int tid = threadIdx.x, lane = tid & 63, wave = tid >> 6;
    const int wr = wave >> 1, wc = wave & 1;
    const int l15 = lane & 15, lq = lane >> 4;

    f32x4 acc[4][4] = {};

    const char* Ab = (const char*)W2 + (size_t)m0 * 1536;
    const uint4* XH = Xhi + (size_t)b * KG * PVOL + n0;
    const uint4* XL = Xlo + (size_t)b * KG * PVOL + n0;

    // per-thread precomputed staging geometry (4 gload pairs)
    // inst = j*4+wave ; fb = inst*1024 + lane*16 ; row = fb>>7 ; sch = slot^row
#define STAGE(bb, it)                                                          \
    {                                                                          \
        _Pragma("unroll")                                                      \
        for (int j = 0; j < 4; ++j) {                                          \
            int inst = j * 4 + wave;                                           \
            int fb = inst * 1024 + (lane << 4);                                \
            int row = fb >> 7;                                                 \
            int sch = ((fb >> 4) & 7) ^ (row & 7);                             \
            GLOAD16(Ab + (size_t)row * 1536 + (it) * 128 + sch * 16,           \
                    (char*)&As[bb][0] + fb);                                   \
            const uint4* plane = (sch < 4) ? XH : XL;                          \
            GLOAD16(plane + ((size_t)((it) * 4 + (sch & 3))) * PVOL + row,     \
                    (char*)&Bs[bb][0] + fb);                                   \
        }                                                                      \
    }

    STAGE(0, 0);

    int cur = 0;
    for (int it = 0; it < 12; ++it) {
        if (it < 11) {
            STAGE(cur ^ 1, it + 1);
            asm volatile("s_waitcnt vmcnt(8)" ::: "memory");   // cur's 8 done; prefetch in flight
        } else {
            asm volatile("s_waitcnt vmcnt(0)" ::: "memory");   // last tile: drain
        }
        __builtin_amdgcn_sched_barrier(0);
        __builtin_amdgcn_s_barrier();
        __builtin_amdgcn_sched_barrier(0);

        bs8 ah[4], al[4], bh[4], bl[4];
        #pragma unroll
        for (int f = 0; f < 4; ++f) {
            int rowA = wr * 64 + f * 16 + l15;
            int swzA = (rowA & 7) << 4;
            ah[f] = *(const bs8*)((const char*)&As[cur][0] + rowA * 128 + ((lq * 16) ^ swzA));
            al[f] = *(const bs8*)((const char*)&As[cur][0] + rowA * 128 + ((64 + lq * 16) ^ swzA));
            int rowB = wc * 64 + f * 16 + l15;
            int swzB = (rowB & 7) << 4;
            bh[f] = *(const bs8*)((const char*)&Bs[cur][0] + rowB * 128 + ((lq * 16) ^ swzB));
            bl[f] = *(const bs8*)((const char*)&Bs[cur][0] + rowB * 128 + ((64 + lq * 16) ^ swzB));
        }
        #pragma unroll
        for (int fm = 0; fm < 4; ++fm)
            #pragma unroll
            for (int fn = 0; fn < 4; ++fn) {
                acc[fm][fn] = __builtin_amdgcn_mfma_f32_16x16x32_bf16(ah[fm], bh[fn], acc[fm][fn], 0, 0, 0);
                acc[fm][fn] = __builtin_amdgcn_mfma_f32_16x16x32_bf16(ah[fm], bl[fn], acc[fm][fn], 0, 0, 0);
                acc[fm][fn] = __builtin_amdgcn_mfma_f32_16x16x32_bf16(al[fm], bh[fn], acc[fm][fn], 0, 0, 0);
            }

        // all waves must finish reading buf[cur] before anyone stages into it
        asm volatile("" ::: "memory");
        __builtin_amdgcn_s_barrier();
        asm volatile("" ::: "memory");
        cur ^= 1;
    }
#undef STAGE

    float* Yp = Y + (size_t)b * MCH * PVOL;
    #pragma unroll
    for (int fm = 0; fm < 4; ++fm)
        #pragma unroll
        for (int j = 0; j < 4; ++j) {
            int m = m0 + wr * 64 + fm * 16 + lq * 4 + j;
            float bias = gbias[m / GG];
            #pragma unroll
            for (int fn = 0; fn < 4; ++fn) {
                int n = n0 + wc * 64 + fn * 16 + l15;
                Yp[(size_t)m * PVOL + n] = acc[fm][fn][j] + bias;
            }
        }
}

// ---------------------------------------------------------------------------
// dwconv v2 (unchanged): depthwise 3x3x3 + t_bias + leaky_relu, z-vec float4.
// ---------------------------------------------------------------------------
__global__ __launch_bounds__(256) void dwconv(const float* __restrict__ Y,
                                              const float* __restrict__ Wt,
                                              const float* __restrict__ tb,
                                              float* __restrict__ O) {
    const int x0 = blockIdx.x * 4;
    const int c  = blockIdx.y;
    const int b  = blockIdx.z;
    const float* __restrict__ Yc = Y + ((size_t)(b * MCH + c)) * PVOL;
    float* __restrict__ Oc = O + ((size_t)(b * MCH + c)) * PVOL;

    __shared__ float s[6][34][40];
    __shared__ float taps[27];
    const int t = threadIdx.x;

    {
        float4 z4 = {0.f, 0.f, 0.f, 0.f};
        float4* sp = (float4*)s;
        for (int i = t; i < 2040; i += 256) sp[i] = z4;
    }
    if (t < 27) taps[t] = Wt[c * 27 + t];
    __syncthreads();

    const int y  = t >> 3;
    const int z0 = (t & 7) * 4;

    {
        float4 r[6];
        #pragma unroll
        for (int lx = 0; lx < 6; ++lx) {
            int x = x0 - 1 + lx;
            bool ok = (x >= 0 && x < 32);
            r[lx] = ok ? *(const float4*)&Yc[(size_t)x * 1024 + y * 32 + z0]
                       : (float4){0.f, 0.f, 0.f, 0.f};
        }
        #pragma unroll
        for (int lx = 0; lx < 6; ++lx)
            *(float4*)&s[lx][1 + y][4 + z0] = r[lx];
    }
    __syncthreads();

    const float t0 = tb[0];
    float w[27];
    #pragma unroll
    for (int j = 0; j < 27; ++j) w[j] = taps[j];

    float Wn[3][3][6];

    #define LOADWIN(slot, plane)                                              \
        {                                                                     \
            _Pragma("unroll")                                                 \
            for (int dy = 0; dy < 3; ++dy) {                                  \
                float4 a = *(const float4*)&s[plane][y + dy][z0];             \
                float4 bq = *(const float4*)&s[plane][y + dy][z0 + 4];        \
                float4 cq = *(const float4*)&s[plane][y + dy][z0 + 8];        \
                Wn[slot][dy][0] = a.w;                                        \
                Wn[slot][dy][1] = bq.x; Wn[slot][dy][2] = bq.y;               \
                Wn[slot][dy][3] = bq.z; Wn[slot][dy][4] = bq.w;               \
                Wn[slot][dy][5] = cq.x;                                       \
            }                                                                 \
        }

    LOADWIN(0, 0)
    LOADWIN(1, 1)

    #pragma unroll
    for (int xi = 0; xi < 4; ++xi) {
        LOADWIN((xi + 2) % 3, (xi + 2))
        const int s0 = xi % 3, s1 = (xi + 1) % 3, s2 = (xi + 2) % 3;
        float4 o;
        #pragma unroll
        for (int zz = 0; zz < 4; ++zz) {
            float a0 = 0.f, a1 = 0.f, a2 = 0.f;
            #pragma unroll
            for (int dy = 0; dy < 3; ++dy)
                #pragma unroll
                for (int dc = 0; dc < 3; ++dc) {
                    a0 += Wn[s0][dy][zz + dc] * w[dy * 3 + dc];
                    a1 += Wn[s1][dy][zz + dc] * w[9 + dy * 3 + dc];
                    a2 += Wn[s2][dy][zz + dc] * w[18 + dy * 3 + dc];
                }
            float v = a0 + a1 + a2 + t0;
            o[zz] = (v > 0.f) ? v : 0.01f * v;
        }
        *(float4*)&Oc[(size_t)(x0 + xi) * 1024 + y * 32 + z0] = o;
    }
    #undef LOADWIN
}

// ---------------------------------------------------------------------------
// Fallback fp32 path (unchanged)
// ---------------------------------------------------------------------------
__global__ void build_weights(const float* __restrict__ gw, const float* __restrict__ tw,
                              float* __restrict__ wmix, float* __restrict__ wt) {
    int idx = blockIdx.x * 256 + threadIdx.x;
    if (idx < MCH * KCH) {
        int c = idx / KCH, k = idx % KCH;
        int o = c / GG, z = c % GG;
        int i = k / GG, g = k % GG;
        wmix[idx] = gw[TAB.shift[z][g] * (OO * II) + o * II + i];
    } else {
        int r = idx - MCH * KCH;
        if (r < MCH * 27) {
            int c = r / 27, j = r % 27;
            wt[r] = tw[(c / GG) * 27 + TAB.rot[c % GG][j]];
        }
    }
}

#define BM 128
#define BN 128
#define BK 16

__global__ __launch_bounds__(256) void gemm_mix(const float* __restrict__ A,
                                                const float* __restrict__ X,
                                                const float* __restrict__ gbias,
                                                float* __restrict__ Y) {
    const int b  = blockIdx.z;
    const int m0 = blockIdx.y * BM;
    const int n0 = blockIdx.x * BN;
    const float* __restrict__ Bp = X + (size_t)b * KCH * PVOL;
    float* __restrict__ Yp = Y + (size_t)b * MCH * PVOL;

    __shared__ float Ash[BK][BM];
    __shared__ float Bsh[BK][BN];

    const int tid = threadIdx.x;
    const int tx = tid % 16;
    const int ty = tid / 16;

    float acc[8][8] = {};

    for (int k0 = 0; k0 < KCH; k0 += BK) {
        #pragma unroll
        for (int r = 0; r < 2; ++r) {
            int tt = tid + r * 256;
            int m = tt / 4;
            int kk = (tt % 4) * 4;
            float4 v = *(const float4*)&A[(m0 + m) * KCH + k0 + kk];
            Ash[kk + 0][m] = v.x; Ash[kk + 1][m] = v.y;
            Ash[kk + 2][m] = v.z; Ash[kk + 3][m] = v.w;
        }
        #pragma unroll
        for (int r = 0; r < 2; ++r) {
            int tt = tid + r * 256;
            int kk = tt / 32;
            int n = (tt % 32) * 4;
            *(float4*)&Bsh[kk][n] = *(const float4*)&Bp[(size_t)(k0 + kk) * PVOL + n0 + n];
        }
        __syncthreads();
        #pragma unroll
        for (int kk = 0; kk < BK; ++kk) {
            float af[8], bf[8];
            #pragma unroll
            for (int i = 0; i < 4; ++i) {
                af[i]     = Ash[kk][ty * 4 + i];
                af[4 + i] = Ash[kk][64 + ty * 4 + i];
                bf[i]     = Bsh[kk][tx * 4 + i];
                bf[4 + i] = Bsh[kk][64 + tx * 4 + i];
            }
            #pragma unroll
            for (int i = 0; i < 8; ++i)
                #pragma unroll
                for (int j = 0; j < 8; ++j)
                    acc[i][j] += af[i] * bf[j];
        }
        __syncthreads();
    }

    #pragma unroll
    for (int i = 0; i < 8; ++i) {
        int m = m0 + ((i < 4) ? (ty * 4 + i) : (64 + ty * 4 + (i - 4)));
        float bias = gbias[m / GG];
        float4 v0 = { acc[i][0] + bias, acc[i][1] + bias, acc[i][2] + bias, acc[i][3] + bias };
        float4 v1 = { acc[i][4] + bias, acc[i][5] + bias, acc[i][6] + bias, acc[i][7] + bias };
        *(float4*)&Yp[(size_t)m * PVOL + n0 + tx * 4]      = v0;
        *(float4*)&Yp[(size_t)m * PVOL + n0 + 64 + tx * 4] = v1;
    }
}

// ---------------------------------------------------------------------------
extern "C" void kernel_launch(void* const* d_in, const int* in_sizes, int n_in,
                              void* d_out, int out_size, void* d_ws, size_t ws_size,
                              hipStream_t stream) {
    const float* x  = (const float*)d_in[0];
    const float* gw = (const float*)d_in[1];
    const float* tw = (const float*)d_in[2];
    const float* gb = (const float*)d_in[3];
    const float* tb = (const float*)d_in[4];
    float* out = (float*)d_out;
    float* ws  = (float*)d_ws;

    // float offsets:
    //   wt   : 0          (10368)
    //   w2   : 10368      (294912 ushorts = 147456 floats)  [mfma] / wmix [fallback]
    //   y    : 157824     (25165824)
    //   xhi  : 25323648   (12582912 float-equiv)
    //   xlo  : 37906560   (12582912)           total 50489472 floats ~= 202 MB
    float*   wt   = ws;
    ushortx* w2   = (ushortx*)(ws + 10368);
    float*   wmix = ws + 10368;
    float*   y    = ws + 157824;
    uint4*   xhi  = (uint4*)(ws + 25323648);
    uint4*   xlo  = (uint4*)(ws + 37906560);

    const size_t need = (size_t)50489472 * 4;  // ~202 MB

    if (ws_size >= need) {
        build_weights2<<<dim3(617), dim3(256), 0, stream>>>(gw, tw, w2, wt);
        convert_x<<<dim3(128, KG, 2), dim3(256), 0, stream>>>(x, xhi, xlo);
        gemm_mfma<<<dim3(256, 3, 2), dim3(256), 0, stream>>>(w2, xhi, xlo, gb, y);
    } else {
        build_weights<<<dim3(617), dim3(256), 0, stream>>>(gw, tw, wmix, wt);
        gemm_mix<<<dim3(PVOL / BN, MCH / BM, 2), dim3(256), 0, stream>>>(wmix, x, gb, y);
    }
    dwconv<<<dim3(8, MCH, 2), dim3(256), 0, stream>>>(y, wt, tb, out);
}

// Round 8
// 298.189 us; speedup vs baseline: 1.0235x; 1.0235x over previous
//
#include <hip/hip_runtime.h>
#include <hip/hip_bf16.h>
#include <stdint.h>

typedef unsigned short ushortx;
typedef __attribute__((ext_vector_type(8))) short bs8;   // 8 bf16 (4 VGPRs)
typedef __attribute__((ext_vector_type(4))) float f32x4; // MFMA acc

// ---------------------------------------------------------------------------
// Compile-time octahedral tables (replicates the reference's itertools order)
// ---------------------------------------------------------------------------
struct Tab {
    int shift[24][24];
    int rot[24][27];
};

constexpr Tab make_tab() {
    Tab t{};
    int mats[24][3][3] = {};
    {
        const int perms[6][3] = {{0,1,2},{0,2,1},{1,0,2},{1,2,0},{2,0,1},{2,1,0}};
        const int sgns[8][3]  = {{1,1,1},{1,1,-1},{1,-1,1},{1,-1,-1},
                                 {-1,1,1},{-1,1,-1},{-1,-1,1},{-1,-1,-1}};
        int n = 0;
        for (int pi = 0; pi < 6; ++pi)
            for (int si = 0; si < 8; ++si) {
                int M[3][3] = {};
                for (int i = 0; i < 3; ++i) M[i][perms[pi][i]] = sgns[si][i];
                int det = M[0][0]*(M[1][1]*M[2][2]-M[1][2]*M[2][1])
                        - M[0][1]*(M[1][0]*M[2][2]-M[1][2]*M[2][0])
                        + M[0][2]*(M[1][0]*M[2][1]-M[1][1]*M[2][0]);
                if (det == 1) {
                    for (int i = 0; i < 3; ++i)
                        for (int j = 0; j < 3; ++j) mats[n][i][j] = M[i][j];
                    ++n;
                }
            }
    }
    for (int g = 0; g < 24; ++g)
        for (int h = 0; h < 24; ++h) {
            int P[3][3] = {};
            for (int i = 0; i < 3; ++i)
                for (int j = 0; j < 3; ++j) {
                    int s = 0;
                    for (int e = 0; e < 3; ++e) s += mats[g][e][i] * mats[h][e][j];
                    P[i][j] = s;
                }
            for (int k = 0; k < 24; ++k) {
                bool eq = true;
                for (int i = 0; i < 3; ++i)
                    for (int j = 0; j < 3; ++j)
                        if (mats[k][i][j] != P[i][j]) eq = false;
                if (eq) t.shift[g][h] = k;
            }
        }
    for (int g = 0; g < 24; ++g)
        for (int j = 0; j < 27; ++j) {
            int co[3] = { j/9 - 1, (j/3)%3 - 1, j%3 - 1 };
            int src[3] = {};
            for (int d = 0; d < 3; ++d) {
                int s = 0;
                for (int e = 0; e < 3; ++e) s += co[e] * mats[g][e][d];
                src[d] = s + 1;
            }
            t.rot[g][j] = src[0]*9 + src[1]*3 + src[2];
        }
    return t;
}

__constant__ Tab TAB = make_tab();

#define GG 24
#define OO 16
#define II 16
#define PVOL 32768
#define MCH 384
#define KCH 384
#define KG  48      // 384 k / 8 per 16B chunk

// bf16 helpers (RNE)
__device__ __forceinline__ unsigned f2bfu(float f) {
    union { float f; unsigned u; } a; a.f = f;
    unsigned r = a.u + 0x7FFFu + ((a.u >> 16) & 1u);
    return r >> 16;
}
__device__ __forceinline__ float bfu2f(unsigned h) {
    union { unsigned u; float f; } a; a.u = h << 16;
    return a.f;
}

#define GLOAD16(gp, lp) \
    __builtin_amdgcn_global_load_lds((const __attribute__((address_space(1))) void*)(gp), \
                                     (__attribute__((address_space(3))) void*)(lp), 16, 0, 0)

// ---------------------------------------------------------------------------
// build_weights2 (unchanged): W2 bf16 [384 m][768 k2], rows = [32 hi | 32 lo]
// ---------------------------------------------------------------------------
__global__ void build_weights2(const float* __restrict__ gw, const float* __restrict__ tw,
                               ushortx* __restrict__ w2, float* __restrict__ wt) {
    int idx = blockIdx.x * 256 + threadIdx.x;
    if (idx < MCH * KCH) {
        int m = idx / KCH, k = idx % KCH;
        int o = m / GG, z = m % GG;
        int i = k / GG, g = k % GG;
        float w = gw[TAB.shift[z][g] * (OO * II) + o * II + i];
        unsigned h = f2bfu(w);
        unsigned l = f2bfu(w - bfu2f(h));
        size_t base = (size_t)m * 768 + (k >> 5) * 64 + (k & 31);
        w2[base]      = (ushortx)h;
        w2[base + 32] = (ushortx)l;
    } else {
        int r = idx - MCH * KCH;
        if (r < MCH * 27) {
            int c = r / 27, j = r % 27;
            wt[r] = tw[(c / GG) * 27 + TAB.rot[c % GG][j]];
        }
    }
}

// ---------------------------------------------------------------------------
// convert_x v3 (unchanged, control): fp32 X -> Xhi/Xlo bf16 chunk planes.
// ---------------------------------------------------------------------------
__global__ __launch_bounds__(256) void convert_x(const float* __restrict__ X,
                                                 uint4* __restrict__ Xhi,
                                                 uint4* __restrict__ Xlo) {
    const int n0 = blockIdx.x * 256, kg = blockIdx.y, b = blockIdx.z;
    __shared__ float s[8][260];
    const int t = threadIdx.x;
    const float* Xb = X + ((size_t)b * KCH + kg * 8) * PVOL;

    {
        const int r0 = t >> 6, c4 = (t & 63) * 4;
        float4 v0 = *(const float4*)&Xb[(size_t)r0 * PVOL + n0 + c4];
        float4 v1 = *(const float4*)&Xb[(size_t)(r0 + 4) * PVOL + n0 + c4];
        *(float4*)&s[r0][c4] = v0;
        *(float4*)&s[r0 + 4][c4] = v1;
    }
    __syncthreads();

    const int n = t;
    float f0 = s[0][n], f1 = s[1][n], f2 = s[2][n], f3 = s[3][n];
    float f4 = s[4][n], f5 = s[5][n], f6 = s[6][n], f7 = s[7][n];

    unsigned h0 = f2bfu(f0), h1 = f2bfu(f1), h2 = f2bfu(f2), h3 = f2bfu(f3);
    unsigned h4 = f2bfu(f4), h5 = f2bfu(f5), h6 = f2bfu(f6), h7 = f2bfu(f7);
    uint4 H = { h0 | (h1 << 16), h2 | (h3 << 16), h4 | (h5 << 16), h6 | (h7 << 16) };

    unsigned l0 = f2bfu(f0 - bfu2f(h0)), l1 = f2bfu(f1 - bfu2f(h1));
    unsigned l2 = f2bfu(f2 - bfu2f(h2)), l3 = f2bfu(f3 - bfu2f(h3));
    unsigned l4 = f2bfu(f4 - bfu2f(h4)), l5 = f2bfu(f5 - bfu2f(h5));
    unsigned l6 = f2bfu(f6 - bfu2f(h6)), l7 = f2bfu(f7 - bfu2f(h7));
    uint4 L = { l0 | (l1 << 16), l2 | (l3 << 16), l4 | (l5 << 16), l6 | (l7 << 16) };

    const size_t ci = ((size_t)(b * KG + kg)) * PVOL + n0 + n;
    Xhi[ci] = H;
    Xlo[ci] = L;
}

// ---------------------------------------------------------------------------
// gemm_mfma v5: A single-buffered (L2-hot restage), B double-buffered with
//   counted vmcnt(4); LDS 48 KB -> 3 blocks/CU (was 64 KB / 2). Y out = bf16.
// ---------------------------------------------------------------------------
__global__ __launch_bounds__(256) void gemm_mfma(const ushortx* __restrict__ W2,
                                                 const uint4* __restrict__ Xhi,
                                                 const uint4* __restrict__ Xlo,
                                                 const float* __restrict__ gbias,
                                                 ushortx* __restrict__ Y) {
    __shared__ ushortx As[8192];      // [128 m][hi 64B | lo 64B] swizzled, 16 KB
    __shared__ ushortx Bs[2][8192];   // double-buffered, 32 KB
    const int b = blockIdx.z, m0 = blockIdx.y * 128, n0 = blockIdx.x * 128;
    const int tid = threadIdx.x, lane = tid & 63, wave = tid >> 6;
    const int wr = wave >> 1, wc = wave & 1;
    const int l15 = lane & 15, lq = lane >> 4;

    f32x4 acc[4][4] = {};

    const char* Ab = (const char*)W2 + (size_t)m0 * 1536;
    const uint4* XH = Xhi + (size_t)b * KG * PVOL + n0;
    const uint4* XL = Xlo + (size_t)b * KG * PVOL + n0;

#define STAGE_A(it)                                                            \
    {                                                                          \
        _Pragma("unroll")                                                      \
        for (int j = 0; j < 4; ++j) {                                          \
            int inst = j * 4 + wave;                                           \
            int fb = inst * 1024 + (lane << 4);                                \
            int row = fb >> 7;                                                 \
            int sch = ((fb >> 4) & 7) ^ (row & 7);                             \
            GLOAD16(Ab + (size_t)row * 1536 + (it) * 128 + sch * 16,           \
                    (char*)As + fb);                                           \
        }                                                                      \
    }
#define STAGE_B(bb, it)                                                        \
    {                                                                          \
        _Pragma("unroll")                                                      \
        for (int j = 0; j < 4; ++j) {                                          \
            int inst = j * 4 + wave;                                           \
            int fb = inst * 1024 + (lane << 4);                                \
            int row = fb >> 7;                                                 \
            int sch = ((fb >> 4) & 7) ^ (row & 7);                             \
            const uint4* plane = (sch < 4) ? XH : XL;                          \
            GLOAD16(plane + ((size_t)((it) * 4 + (sch & 3))) * PVOL + row,     \
                    (char*)&Bs[bb][0] + fb);                                   \
        }                                                                      \
    }

    STAGE_B(0, 0);

    int cur = 0;
    for (int it = 0; it < 12; ++it) {
        STAGE_A(it);
        if (it < 11) {
            STAGE_B(cur ^ 1, it + 1);
            // outstanding after drain: 4 B-next loads (kept in flight)
            asm volatile("s_waitcnt vmcnt(4)" ::: "memory");
        } else {
            asm volatile("s_waitcnt vmcnt(0)" ::: "memory");
        }
        __builtin_amdgcn_sched_barrier(0);
        __builtin_amdgcn_s_barrier();
        __builtin_amdgcn_sched_barrier(0);

        bs8 ah[4], al[4], bh[4], bl[4];
        #pragma unroll
        for (int f = 0; f < 4; ++f) {
            int rowA = wr * 64 + f * 16 + l15;
            int swzA = (rowA & 7) << 4;
            ah[f] = *(const bs8*)((const char*)As + rowA * 128 + ((lq * 16) ^ swzA));
            al[f] = *(const bs8*)((const char*)As + rowA * 128 + ((64 + lq * 16) ^ swzA));
            int rowB = wc * 64 + f * 16 + l15;
            int swzB = (rowB & 7) << 4;
            bh[f] = *(const bs8*)((const char*)&Bs[cur][0] + rowB * 128 + ((lq * 16) ^ swzB));
            bl[f] = *(const bs8*)((const char*)&Bs[cur][0] + rowB * 128 + ((64 + lq * 16) ^ swzB));
        }
        #pragma unroll
        for (int fm = 0; fm < 4; ++fm)
            #pragma unroll
            for (int fn = 0; fn < 4; ++fn) {
                acc[fm][fn] = __builtin_amdgcn_mfma_f32_16x16x32_bf16(ah[fm], bh[fn], acc[fm][fn], 0, 0, 0);
                acc[fm][fn] = __builtin_amdgcn_mfma_f32_16x16x32_bf16(ah[fm], bl[fn], acc[fm][fn], 0, 0, 0);
                acc[fm][fn] = __builtin_amdgcn_mfma_f32_16x16x32_bf16(al[fm], bh[fn], acc[fm][fn], 0, 0, 0);
            }

        // all waves done reading As / Bs[cur] before next iter restages
        asm volatile("" ::: "memory");
        __builtin_amdgcn_s_barrier();
        asm volatile("" ::: "memory");
        cur ^= 1;
    }
#undef STAGE_A
#undef STAGE_B

    ushortx* Yp = Y + (size_t)b * MCH * PVOL;
    #pragma unroll
    for (int fm = 0; fm < 4; ++fm)
        #pragma unroll
        for (int j = 0; j < 4; ++j) {
            int m = m0 + wr * 64 + fm * 16 + lq * 4 + j;
            float bias = gbias[m / GG];
            #pragma unroll
            for (int fn = 0; fn < 4; ++fn) {
                int n = n0 + wc * 64 + fn * 16 + l15;
                Yp[(size_t)m * PVOL + n] = (ushortx)f2bfu(acc[fm][fn][j] + bias);
            }
        }
}

// ---------------------------------------------------------------------------
// dwconv v3: x-streaming. One block per (channel, batch); rotating 4-plane
//   LDS [4][34][40]; each Y bf16 plane read from HBM exactly once (1.0x vs
//   1.5x slab-4); plane prefetched 1 step ahead into regs; ONE raw barrier
//   per step (write-slot is disjoint from read-slots within a step).
// ---------------------------------------------------------------------------
__global__ __launch_bounds__(256) void dwconv(const ushortx* __restrict__ Y,
                                              const float* __restrict__ Wt,
                                              const float* __restrict__ tb,
                                              float* __restrict__ O) {
    const int c = blockIdx.x;
    const int b = blockIdx.y;
    const ushortx* __restrict__ Yc = Y + ((size_t)(b * MCH + c)) * PVOL;
    float* __restrict__ Oc = O + ((size_t)(b * MCH + c)) * PVOL;

    __shared__ float s[4][34][40];   // rotating x-planes, halos zero
    __shared__ float taps[27];
    const int t = threadIdx.x;
    const int y  = t >> 3;          // 0..31
    const int z0 = (t & 7) * 4;     // 0..28
    const int yz = y * 32 + z0;

    {   // zero all 4 plane slots (halos + slot3 = plane -1)
        float4 z4 = {0.f, 0.f, 0.f, 0.f};
        float4* sp = (float4*)s;
        for (int i = t; i < 4 * 34 * 40 / 4; i += 256) sp[i] = z4;
    }
    if (t < 27) taps[t] = Wt[c * 27 + t];
    __syncthreads();

#define LDP(a) ({                                                             \
        ushort4 v_ = *(const ushort4*)&Yc[(size_t)(a) * 1024 + yz];           \
        float4 f_;                                                            \
        f_.x = bfu2f(v_.x); f_.y = bfu2f(v_.y);                               \
        f_.z = bfu2f(v_.z); f_.w = bfu2f(v_.w);                               \
        f_; })

    // planes 0,1 -> LDS slots 0,1 ; plane 2 prefetched to regs
    {
        float4 p0 = LDP(0), p1 = LDP(1);
        *(float4*)&s[0][1 + y][4 + z0] = p0;
        *(float4*)&s[1][1 + y][4 + z0] = p1;
    }
    __syncthreads();
    float4 rplane = LDP(2);

    const float t0 = tb[0];
    float w[27];
    #pragma unroll
    for (int j = 0; j < 27; ++j) w[j] = taps[j];

    float Wn[3][3][6];   // [slot][dy][z0-1..z0+4]

#define LOADWIN(WS, LSLOT)                                                    \
    {                                                                         \
        _Pragma("unroll")                                                     \
        for (int dy = 0; dy < 3; ++dy) {                                      \
            float4 a_ = *(const float4*)&s[LSLOT][y + dy][z0];                \
            float4 b_ = *(const float4*)&s[LSLOT][y + dy][z0 + 4];            \
            float4 c_ = *(const float4*)&s[LSLOT][y + dy][z0 + 8];            \
            Wn[WS][dy][0] = a_.w;                                             \
            Wn[WS][dy][1] = b_.x; Wn[WS][dy][2] = b_.y;                       \
            Wn[WS][dy][3] = b_.z; Wn[WS][dy][4] = b_.w;                       \
            Wn[WS][dy][5] = c_.x;                                             \
        }                                                                     \
    }

    LOADWIN(2, 3)   // plane -1 (zeros)
    LOADWIN(0, 0)   // plane 0

#define BODY(x, SA, SB, SC)                                                   \
    {                                                                         \
        float4 rn = ((x) + 3 < 32) ? LDP((x) + 3) : (float4){0.f,0.f,0.f,0.f};\
        LOADWIN(SC, ((x) + 1) & 3)                                            \
        float4 o;                                                             \
        _Pragma("unroll")                                                     \
        for (int zz = 0; zz < 4; ++zz) {                                      \
            float a0 = 0.f, a1 = 0.f, a2 = 0.f;                               \
            _Pragma("unroll")                                                 \
            for (int dy = 0; dy < 3; ++dy)                                    \
                _Pragma("unroll")                                             \
                for (int dc = 0; dc < 3; ++dc) {                              \
                    a0 += Wn[SA][dy][zz + dc] * w[dy * 3 + dc];               \
                    a1 += Wn[SB][dy][zz + dc] * w[9 + dy * 3 + dc];           \
                    a2 += Wn[SC][dy][zz + dc] * w[18 + dy * 3 + dc];          \
                }                                                             \
            float v_ = a0 + a1 + a2 + t0;                                     \
            o[zz] = (v_ > 0.f) ? v_ : 0.01f * v_;                             \
        }                                                                     \
        *(float4*)&Oc[(size_t)(x) * 1024 + yz] = o;                           \
        *(float4*)&s[((x) + 2) & 3][1 + y][4 + z0] = rplane;                  \
        asm volatile("s_waitcnt lgkmcnt(0)" ::: "memory");                    \
        __builtin_amdgcn_s_barrier();                                         \
        rplane = rn;                                                          \
    }

    for (int xb = 0; xb < 30; xb += 3) {
        BODY(xb + 0, 2, 0, 1)
        BODY(xb + 1, 0, 1, 2)
        BODY(xb + 2, 1, 2, 0)
    }
    BODY(30, 2, 0, 1)
    BODY(31, 0, 1, 2)
#undef BODY
#undef LOADWIN
#undef LDP
}

// ---------------------------------------------------------------------------
// Fallback fp32 path (kept for small-ws safety; not used when ws suffices)
// ---------------------------------------------------------------------------
__global__ void build_weights(const float* __restrict__ gw, const float* __restrict__ tw,
                              float* __restrict__ wmix, float* __restrict__ wt) {
    int idx = blockIdx.x * 256 + threadIdx.x;
    if (idx < MCH * KCH) {
        int c = idx / KCH, k = idx % KCH;
        int o = c / GG, z = c % GG;
        int i = k / GG, g = k % GG;
        wmix[idx] = gw[TAB.shift[z][g] * (OO * II) + o * II + i];
    } else {
        int r = idx - MCH * KCH;
        if (r < MCH * 27) {
            int c = r / 27, j = r % 27;
            wt[r] = tw[(c / GG) * 27 + TAB.rot[c % GG][j]];
        }
    }
}

__global__ __launch_bounds__(256) void gemm_mix(const float* __restrict__ A,
                                                const float* __restrict__ X,
                                                const float* __restrict__ gbias,
                                                float* __restrict__ Yp_) {
    const int b  = blockIdx.z;
    const int m0 = blockIdx.y * 128;
    const int n0 = blockIdx.x * 128;
    const float* __restrict__ Bp = X + (size_t)b * KCH * PVOL;
    float* __restrict__ Yp = Yp_ + (size_t)b * MCH * PVOL;

    __shared__ float Ash[16][128];
    __shared__ float Bsh[16][128];

    const int tid = threadIdx.x;
    const int tx = tid % 16;
    const int ty = tid / 16;

    float acc[8][8] = {};

    for (int k0 = 0; k0 < KCH; k0 += 16) {
        #pragma unroll
        for (int r = 0; r < 2; ++r) {
            int tt = tid + r * 256;
            int m = tt / 4;
            int kk = (tt % 4) * 4;
            float4 v = *(const float4*)&A[(m0 + m) * KCH + k0 + kk];
            Ash[kk + 0][m] = v.x; Ash[kk + 1][m] = v.y;
            Ash[kk + 2][m] = v.z; Ash[kk + 3][m] = v.w;
        }
        #pragma unroll
        for (int r = 0; r < 2; ++r) {
            int tt = tid + r * 256;
            int kk = tt / 32;
            int n = (tt % 32) * 4;
            *(float4*)&Bsh[kk][n] = *(const float4*)&Bp[(size_t)(k0 + kk) * PVOL + n0 + n];
        }
        __syncthreads();
        #pragma unroll
        for (int kk = 0; kk < 16; ++kk) {
            float af[8], bf[8];
            #pragma unroll
            for (int i = 0; i < 4; ++i) {
                af[i]     = Ash[kk][ty * 4 + i];
                af[4 + i] = Ash[kk][64 + ty * 4 + i];
                bf[i]     = Bsh[kk][tx * 4 + i];
                bf[4 + i] = Bsh[kk][64 + tx * 4 + i];
            }
            #pragma unroll
            for (int i = 0; i < 8; ++i)
                #pragma unroll
                for (int j = 0; j < 8; ++j)
                    acc[i][j] += af[i] * bf[j];
        }
        __syncthreads();
    }

    #pragma unroll
    for (int i = 0; i < 8; ++i) {
        int m = m0 + ((i < 4) ? (ty * 4 + i) : (64 + ty * 4 + (i - 4)));
        float bias = gbias[m / GG];
        float4 v0 = { acc[i][0] + bias, acc[i][1] + bias, acc[i][2] + bias, acc[i][3] + bias };
        float4 v1 = { acc[i][4] + bias, acc[i][5] + bias, acc[i][6] + bias, acc[i][7] + bias };
        *(float4*)&Yp[(size_t)m * PVOL + n0 + tx * 4]      = v0;
        *(float4*)&Yp[(size_t)m * PVOL + n0 + 64 + tx * 4] = v1;
    }
}

// fp32-Y dwconv (fallback path only) — R7's slab-4 version
__global__ __launch_bounds__(256) void dwconv_f32(const float* __restrict__ Y,
                                                  const float* __restrict__ Wt,
                                                  const float* __restrict__ tb,
                                                  float* __restrict__ O) {
    const int x0 = blockIdx.x * 4;
    const int c  = blockIdx.y;
    const int b  = blockIdx.z;
    const float* __restrict__ Yc = Y + ((size_t)(b * MCH + c)) * PVOL;
    float* __restrict__ Oc = O + ((size_t)(b * MCH + c)) * PVOL;

    __shared__ float s[6][34][40];
    __shared__ float taps[27];
    const int t = threadIdx.x;

    {
        float4 z4 = {0.f, 0.f, 0.f, 0.f};
        float4* sp = (float4*)s;
        for (int i = t; i < 2040; i += 256) sp[i] = z4;
    }
    if (t < 27) taps[t] = Wt[c * 27 + t];
    __syncthreads();

    const int y  = t >> 3;
    const int z0 = (t & 7) * 4;

    {
        float4 r[6];
        #pragma unroll
        for (int lx = 0; lx < 6; ++lx) {
            int x = x0 - 1 + lx;
            bool ok = (x >= 0 && x < 32);
            r[lx] = ok ? *(const float4*)&Yc[(size_t)x * 1024 + y * 32 + z0]
                       : (float4){0.f, 0.f, 0.f, 0.f};
        }
        #pragma unroll
        for (int lx = 0; lx < 6; ++lx)
            *(float4*)&s[lx][1 + y][4 + z0] = r[lx];
    }
    __syncthreads();

    const float t0 = tb[0];
    float w[27];
    #pragma unroll
    for (int j = 0; j < 27; ++j) w[j] = taps[j];

    float Wn[3][3][6];

    #define LOADWIN(slot, plane)                                              \
        {                                                                     \
            _Pragma("unroll")                                                 \
            for (int dy = 0; dy < 3; ++dy) {                                  \
                float4 a = *(const float4*)&s[plane][y + dy][z0];             \
                float4 bq = *(const float4*)&s[plane][y + dy][z0 + 4];        \
                float4 cq = *(const float4*)&s[plane][y + dy][z0 + 8];        \
                Wn[slot][dy][0] = a.w;                                        \
                Wn[slot][dy][1] = bq.x; Wn[slot][dy][2] = bq.y;               \
                Wn[slot][dy][3] = bq.z; Wn[slot][dy][4] = bq.w;               \
                Wn[slot][dy][5] = cq.x;                                       \
            }                                                                 \
        }

    LOADWIN(0, 0)
    LOADWIN(1, 1)

    #pragma unroll
    for (int xi = 0; xi < 4; ++xi) {
        LOADWIN((xi + 2) % 3, (xi + 2))
        const int s0 = xi % 3, s1 = (xi + 1) % 3, s2 = (xi + 2) % 3;
        float4 o;
        #pragma unroll
        for (int zz = 0; zz < 4; ++zz) {
            float a0 = 0.f, a1 = 0.f, a2 = 0.f;
            #pragma unroll
            for (int dy = 0; dy < 3; ++dy)
                #pragma unroll
                for (int dc = 0; dc < 3; ++dc) {
                    a0 += Wn[s0][dy][zz + dc] * w[dy * 3 + dc];
                    a1 += Wn[s1][dy][zz + dc] * w[9 + dy * 3 + dc];
                    a2 += Wn[s2][dy][zz + dc] * w[18 + dy * 3 + dc];
                }
            float v = a0 + a1 + a2 + t0;
            o[zz] = (v > 0.f) ? v : 0.01f * v;
        }
        *(float4*)&Oc[(size_t)(x0 + xi) * 1024 + y * 32 + z0] = o;
    }
    #undef LOADWIN
}

// ---------------------------------------------------------------------------
extern "C" void kernel_launch(void* const* d_in, const int* in_sizes, int n_in,
                              void* d_out, int out_size, void* d_ws, size_t ws_size,
                              hipStream_t stream) {
    const float* x  = (const float*)d_in[0];
    const float* gw = (const float*)d_in[1];
    const float* tw = (const float*)d_in[2];
    const float* gb = (const float*)d_in[3];
    const float* tb = (const float*)d_in[4];
    float* out = (float*)d_out;
    float* ws  = (float*)d_ws;

    // float offsets:
    //   wt   : 0          (10368)
    //   w2   : 10368      (294912 ushorts)  [mfma] / wmix fp32 [fallback]
    //   y    : 157824     (bf16: 25165824 ushorts | fallback fp32: 25165824 f)
    //   xhi  : 25323648   ; xlo : 37906560     total 50489472 floats ~= 202 MB
    float*   wt    = ws;
    ushortx* w2    = (ushortx*)(ws + 10368);
    float*   wmix  = ws + 10368;
    ushortx* y16   = (ushortx*)(ws + 157824);
    float*   y32   = ws + 157824;
    uint4*   xhi   = (uint4*)(ws + 25323648);
    uint4*   xlo   = (uint4*)(ws + 37906560);

    const size_t need = (size_t)50489472 * 4;  // ~202 MB

    if (ws_size >= need) {
        build_weights2<<<dim3(617), dim3(256), 0, stream>>>(gw, tw, w2, wt);
        convert_x<<<dim3(128, KG, 2), dim3(256), 0, stream>>>(x, xhi, xlo);
        gemm_mfma<<<dim3(256, 3, 2), dim3(256), 0, stream>>>(w2, xhi, xlo, gb, y16);
        dwconv<<<dim3(MCH, 2), dim3(256), 0, stream>>>(y16, wt, tb, out);
    } else {
        build_weights<<<dim3(617), dim3(256), 0, stream>>>(gw, tw, wmix, wt);
        gemm_mix<<<dim3(PVOL / 128, MCH / 128, 2), dim3(256), 0, stream>>>(wmix, x, gb, y32);
        dwconv_f32<<<dim3(8, MCH, 2), dim3(256), 0, stream>>>(y32, wt, tb, out);
    }
}